// Round 1
// baseline (448.451 us; speedup 1.0000x reference)
//
#include <hip/hip_runtime.h>
#include <hip/hip_bf16.h>

#define NTOK 49
#define NP 64
#define CDIM 256
#define NH 8
#define SCALE 0.17677669529663687f

#define SX_LD 264   // [64][256] bf16 tile row stride (528B: 16B-aligned, 2-way-conflict max)
#define SV_LD 72    // Vt [256][64] row stride (144B)
#define SP_LD 72    // P  [64][64] row stride

using f32x4  = __attribute__((ext_vector_type(4))) float;
using bf16x8 = __attribute__((ext_vector_type(8))) short;

__device__ __forceinline__ unsigned f2bf_u(float f) {
  union { float f; unsigned u; } c; c.f = f;
  return (c.u + 0x7fffu + ((c.u >> 16) & 1u)) >> 16;   // RNE
}
__device__ __forceinline__ unsigned pk2(float a, float b) {
  return f2bf_u(a) | (f2bf_u(b) << 16);
}

// ---------------- prep: bf16 weights (scale folded into Wq), scaled bias, attention bias table
__global__ void prep_kernel(const float* __restrict__ qkv_w, const float* __restrict__ qkv_b,
                            const float* __restrict__ proj_w,
                            const float* __restrict__ rpb, const int* __restrict__ rel,
                            short* __restrict__ wqkv, short* __restrict__ wp,
                            float* __restrict__ bias_s, float* __restrict__ bias_att) {
  int i = blockIdx.x * 256 + threadIdx.x;
  if (i < 768 * 256) {
    int j = i >> 8;
    float v = qkv_w[i] * (j < 256 ? SCALE : 1.0f);
    wqkv[i] = (short)f2bf_u(v);
    return;
  }
  i -= 768 * 256;
  if (i < 256 * 256) { wp[i] = (short)f2bf_u(proj_w[i]); return; }
  i -= 256 * 256;
  if (i < 768) { bias_s[i] = qkv_b[i] * (i < 256 ? SCALE : 1.0f); return; }
  i -= 768;
  if (i < NH * NP * NP) {
    int h = i >> 12, rem = i & 4095, r = rem >> 6, c = rem & 63;
    float v;
    if (c >= NTOK)      v = -1e30f;      // mask padded key columns
    else if (r >= NTOK) v = 0.0f;        // padded query rows: any finite value
    else                v = rpb[rel[r * NTOK + c] * NH + h];
    bias_att[i] = v;
  }
}

// col-split 64x256(x256) GEMM: wave w computes output cols [64w,64w+64), all 64 rows.
// A from LDS (bf16 [64][SX_LD]); B^T = weight rows (bf16 [*,256] row-major); bias init.
__device__ __forceinline__ void gemm64(const short* sa, const short* __restrict__ wg,
                                       const float* __restrict__ bias,
                                       f32x4 acc[4][4], int w, int lr, int lg) {
  #pragma unroll
  for (int ct = 0; ct < 4; ++ct) {
    const int j0 = w * 64 + ct * 16;
    const short* wrow = wg + (j0 + lr) * CDIM + lg * 8;
    bf16x8 bfr[8];
    #pragma unroll
    for (int k = 0; k < 8; ++k) bfr[k] = *(const bf16x8*)(wrow + k * 32);
    const float bv = bias[j0 + lr];
    #pragma unroll
    for (int rt = 0; rt < 4; ++rt) {
      f32x4 a; a[0] = bv; a[1] = bv; a[2] = bv; a[3] = bv;
      const short* arow = sa + (rt * 16 + lr) * SX_LD + lg * 8;
      #pragma unroll
      for (int k = 0; k < 8; ++k) {
        const bf16x8 af = *(const bf16x8*)(arow + k * 32);
        a = __builtin_amdgcn_mfma_f32_16x16x32_bf16(af, bfr[k], a, 0, 0, 0);
      }
      acc[rt][ct] = a;
    }
  }
}

__global__ __launch_bounds__(256, 2)
void fused_attn(const float* __restrict__ x1, const float* __restrict__ x2,
                const short* __restrict__ wqkv, const float* __restrict__ bias_s,
                const short* __restrict__ wp, const float* __restrict__ proj_b,
                const float* __restrict__ bias_att, float* __restrict__ out) {
  extern __shared__ short lds[];
  short* sx = lds;                    // [64][SX_LD]  x1->Q (in place), then x2->K, then O
  short* sv = lds + NP * SX_LD;       // [256][SV_LD] V^T (feature-major)
  short* sp = sv + CDIM * SV_LD;      // [64][SP_LD]  P (wave-private rows)

  const int tid = threadIdx.x;
  const int w = tid >> 6, lane = tid & 63;
  const int lr = lane & 15, lg = lane >> 4;
  const int b = blockIdx.x;

  // ---- stage x1 (f32 -> bf16, rows 49..63 zeroed) ----
  {
    const float* xg = x1 + (size_t)b * NTOK * CDIM;
    for (int i = tid; i < NP * 64; i += 256) {
      int row = i >> 6, c4 = i & 63;
      uint2 pkv = make_uint2(0u, 0u);
      if (row < NTOK) {
        const float4 v = *(const float4*)(xg + row * CDIM + c4 * 4);
        pkv.x = pk2(v.x, v.y); pkv.y = pk2(v.z, v.w);
      }
      *(uint2*)(sx + row * SX_LD + c4 * 4) = pkv;
    }
  }
  __syncthreads();

  f32x4 acc[4][4];

  // ---- Q = x1 @ Wq^T (pre-scaled) ----
  gemm64(sx, wqkv, bias_s, acc, w, lr, lg);
  __syncthreads();                       // all waves done reading x1
  #pragma unroll
  for (int rt = 0; rt < 4; ++rt)
    #pragma unroll
    for (int ct = 0; ct < 4; ++ct)
      #pragma unroll
      for (int r = 0; r < 4; ++r)
        sx[(rt * 16 + lg * 4 + r) * SX_LD + w * 64 + ct * 16 + lr] = (short)f2bf_u(acc[rt][ct][r]);
  __syncthreads();

  // per-wave Q A-fragments (wave w owns query rows 16w..16w+15), one per head
  bf16x8 qa[8];
  {
    const short* qrow = sx + (w * 16 + lr) * SX_LD + lg * 8;
    #pragma unroll
    for (int h = 0; h < 8; ++h) qa[h] = *(const bf16x8*)(qrow + h * 32);
  }
  __syncthreads();                       // everyone grabbed Q before overwrite

  // ---- stage x2 ----
  {
    const float* xg = x2 + (size_t)b * NTOK * CDIM;
    for (int i = tid; i < NP * 64; i += 256) {
      int row = i >> 6, c4 = i & 63;
      uint2 pkv = make_uint2(0u, 0u);
      if (row < NTOK) {
        const float4 v = *(const float4*)(xg + row * CDIM + c4 * 4);
        pkv.x = pk2(v.x, v.y); pkv.y = pk2(v.z, v.w);
      }
      *(uint2*)(sx + row * SX_LD + c4 * 4) = pkv;
    }
  }
  __syncthreads();

  // ---- V = x2 @ Wv^T, stored transposed: sv[feature][token] ----
  gemm64(sx, wqkv + 512 * CDIM, bias_s + 512, acc, w, lr, lg);
  #pragma unroll
  for (int rt = 0; rt < 4; ++rt)
    #pragma unroll
    for (int ct = 0; ct < 4; ++ct) {
      uint2 pkv = make_uint2(pk2(acc[rt][ct][0], acc[rt][ct][1]),
                             pk2(acc[rt][ct][2], acc[rt][ct][3]));
      *(uint2*)(sv + (w * 64 + ct * 16 + lr) * SV_LD + rt * 16 + lg * 4) = pkv;
    }

  // ---- K = x2 @ Wk^T (x2 still intact) ----
  gemm64(sx, wqkv + 256 * CDIM, bias_s + 256, acc, w, lr, lg);
  __syncthreads();                       // all reads of x2 done
  #pragma unroll
  for (int rt = 0; rt < 4; ++rt)
    #pragma unroll
    for (int ct = 0; ct < 4; ++ct)
      #pragma unroll
      for (int r = 0; r < 4; ++r)
        sx[(rt * 16 + lg * 4 + r) * SX_LD + w * 64 + ct * 16 + lr] = (short)f2bf_u(acc[rt][ct][r]);
  __syncthreads();                       // K (and V^T) visible

  // ---- per-head attention; wave w owns query rows 16w..16w+15 (no barriers needed) ----
  f32x4 oacc[16];
  #pragma unroll
  for (int t = 0; t < 16; ++t) { oacc[t][0] = 0; oacc[t][1] = 0; oacc[t][2] = 0; oacc[t][3] = 0; }

  for (int h = 0; h < NH; ++h) {
    const float* bh = bias_att + h * NP * NP + (w * 16 + lg * 4) * NP;
    f32x4 s[4];
    #pragma unroll
    for (int ct = 0; ct < 4; ++ct) {
      f32x4 sb;
      #pragma unroll
      for (int r = 0; r < 4; ++r) sb[r] = bh[r * NP + ct * 16 + lr];
      const bf16x8 kb = *(const bf16x8*)(sx + (ct * 16 + lr) * SX_LD + h * 32 + lg * 8);
      s[ct] = __builtin_amdgcn_mfma_f32_16x16x32_bf16(qa[h], kb, sb, 0, 0, 0);
    }
    // row softmax: row = 16w + lg*4 + r; its 64 cols live in 16 lanes (same lg) x 4 ct
    float mx[4], si[4];
    #pragma unroll
    for (int r = 0; r < 4; ++r) {
      float m = fmaxf(fmaxf(s[0][r], s[1][r]), fmaxf(s[2][r], s[3][r]));
      m = fmaxf(m, __shfl_xor(m, 1, 64));
      m = fmaxf(m, __shfl_xor(m, 2, 64));
      m = fmaxf(m, __shfl_xor(m, 4, 64));
      m = fmaxf(m, __shfl_xor(m, 8, 64));
      mx[r] = m;
    }
    #pragma unroll
    for (int ct = 0; ct < 4; ++ct)
      #pragma unroll
      for (int r = 0; r < 4; ++r)
        s[ct][r] = __expf(s[ct][r] - mx[r]);
    #pragma unroll
    for (int r = 0; r < 4; ++r) {
      float t = s[0][r] + s[1][r] + s[2][r] + s[3][r];
      t += __shfl_xor(t, 1, 64);
      t += __shfl_xor(t, 2, 64);
      t += __shfl_xor(t, 4, 64);
      t += __shfl_xor(t, 8, 64);
      si[r] = __builtin_amdgcn_rcpf(t);
    }
    #pragma unroll
    for (int ct = 0; ct < 4; ++ct)
      #pragma unroll
      for (int r = 0; r < 4; ++r)
        sp[(w * 16 + lg * 4 + r) * SP_LD + ct * 16 + lr] = (short)f2bf_u(s[ct][r] * si[r]);
    // PV: O(rows 16w..) cols h*32 + jt*16
    #pragma unroll
    for (int kk = 0; kk < 2; ++kk) {
      const bf16x8 pa = *(const bf16x8*)(sp + (w * 16 + lr) * SP_LD + kk * 32 + lg * 8);
      #pragma unroll
      for (int jt = 0; jt < 2; ++jt) {
        const bf16x8 vb = *(const bf16x8*)(sv + (h * 32 + jt * 16 + lr) * SV_LD + kk * 32 + lg * 8);
        oacc[h * 2 + jt] = __builtin_amdgcn_mfma_f32_16x16x32_bf16(pa, vb, oacc[h * 2 + jt], 0, 0, 0);
      }
    }
  }

  // ---- O -> LDS (over K, dead now), then proj ----
  __syncthreads();                       // all waves done reading K
  #pragma unroll
  for (int t = 0; t < 16; ++t)
    #pragma unroll
    for (int r = 0; r < 4; ++r)
      sx[(w * 16 + lg * 4 + r) * SX_LD + t * 16 + lr] = (short)f2bf_u(oacc[t][r]);
  __syncthreads();

  gemm64(sx, wp, proj_b, acc, w, lr, lg);

  float* og = out + (size_t)b * NTOK * CDIM;
  #pragma unroll
  for (int rt = 0; rt < 4; ++rt)
    #pragma unroll
    for (int r = 0; r < 4; ++r) {
      const int row = rt * 16 + lg * 4 + r;
      if (row < NTOK) {
        #pragma unroll
        for (int ct = 0; ct < 4; ++ct)
          og[row * CDIM + w * 64 + ct * 16 + lr] = acc[rt][ct][r];
      }
    }
}

extern "C" void kernel_launch(void* const* d_in, const int* in_sizes, int n_in,
                              void* d_out, int out_size, void* d_ws, size_t ws_size,
                              hipStream_t stream) {
  const float* x1     = (const float*)d_in[0];
  const float* x2     = (const float*)d_in[1];
  const float* qkv_w  = (const float*)d_in[2];
  const float* qkv_b  = (const float*)d_in[3];
  const float* proj_w = (const float*)d_in[4];
  const float* proj_b = (const float*)d_in[5];
  const float* rpb    = (const float*)d_in[6];
  const int*   rel    = (const int*)d_in[7];

  char* ws = (char*)d_ws;
  short* wqkv     = (short*)ws;                                   // 768*256 bf16
  short* wp       = (short*)(ws + 768 * 256 * 2);                 // 256*256 bf16
  float* bias_s   = (float*)(ws + 768 * 256 * 2 + 256 * 256 * 2); // 768 f32
  float* bias_att = (float*)(ws + 768 * 256 * 2 + 256 * 256 * 2 + 768 * 4); // 8*64*64 f32

  const int prep_total = 768 * 256 + 256 * 256 + 768 + NH * NP * NP;  // 295680
  prep_kernel<<<(prep_total + 255) / 256, 256, 0, stream>>>(
      qkv_w, qkv_b, proj_w, rpb, rel, wqkv, wp, bias_s, bias_att);

  const int Bn = in_sizes[0] / (NTOK * CDIM);
  const size_t shmem = (size_t)(NP * SX_LD + CDIM * SV_LD + NP * SP_LD) * sizeof(short); // 79872
  (void)hipFuncSetAttribute((const void*)fused_attn,
                            hipFuncAttributeMaxDynamicSharedMemorySize, (int)shmem);
  fused_attn<<<Bn, 256, shmem, stream>>>(x1, x2, wqkv, bias_s, wp, proj_b, bias_att,
                                         (float*)d_out);
}

// Round 2
// 359.454 us; speedup vs baseline: 1.2476x; 1.2476x over previous
//
#include <hip/hip_runtime.h>
#include <hip/hip_bf16.h>

#define NTOK 49
#define NP 64
#define CDIM 256
#define NH 8
#define SCALE 0.17677669529663687f

// LDS (all XOR-16 swizzled, exact fit 2 blocks/CU):
//   sx : [64][256] bf16  (x1 -> Q in place -> x2 -> K in place -> O)   32768 B
//   sv : [256][64] bf16  V^T feature-major                              32768 B
//   sp : 8 waves x [16][64] bf16  P (wave-private)                      16384 B
#define SX_BYTES 32768
#define SV_BYTES 32768
#define SP_BYTES 16384

using f32x4  = __attribute__((ext_vector_type(4))) float;
using bf16x8 = __attribute__((ext_vector_type(8))) short;

__device__ __forceinline__ unsigned f2bf_u(float f) {
  union { float f; unsigned u; } c; c.f = f;
  return (c.u + 0x7fffu + ((c.u >> 16) & 1u)) >> 16;   // RNE
}
__device__ __forceinline__ unsigned pk2(float a, float b) {
  return f2bf_u(a) | (f2bf_u(b) << 16);
}

// byte-offset helpers with XOR-16 swizzle (row-bit into 16B-slot bit)
__device__ __forceinline__ int sx_b(int row, int col) {   // bf16 [64][256]
  return (row * 512 + col * 2) ^ ((row & 7) << 4);
}
__device__ __forceinline__ int sv_b(int feat, int tok) {  // bf16 [256][64]
  return (feat * 128 + tok * 2) ^ ((feat & 7) << 4);
}
__device__ __forceinline__ int sp_b(int w, int row, int key) { // bf16 8x[16][64]
  return w * 2048 + ((row * 128 + key * 2) ^ ((row & 7) << 4));
}
__device__ __forceinline__ int so_b(int row, int col) {   // f32 [64][128] (out stage)
  return (row * 512 + col * 4) ^ ((row & 7) << 4);
}

// ---------------- prep: bf16 weights (scale folded into Wq), attention bias table
__global__ void prep_kernel(const float* __restrict__ qkv_w, const float* __restrict__ qkv_b,
                            const float* __restrict__ proj_w,
                            const float* __restrict__ rpb, const int* __restrict__ rel,
                            short* __restrict__ wqkv, short* __restrict__ wp,
                            float* __restrict__ bias_s, float* __restrict__ bias_att) {
  int i = blockIdx.x * 256 + threadIdx.x;
  if (i < 768 * 256) {
    int j = i >> 8;
    float v = qkv_w[i] * (j < 256 ? SCALE : 1.0f);
    wqkv[i] = (short)f2bf_u(v);
    return;
  }
  i -= 768 * 256;
  if (i < 256 * 256) { wp[i] = (short)f2bf_u(proj_w[i]); return; }
  i -= 256 * 256;
  if (i < 768) { bias_s[i] = qkv_b[i] * (i < 256 ? SCALE : 1.0f); return; }
  i -= 768;
  if (i < NH * NP * NP) {
    int h = i >> 12, rem = i & 4095, r = rem >> 6, c = rem & 63;
    float v;
    if (c >= NTOK)      v = -1e30f;      // mask padded key columns
    else if (r >= NTOK) v = 0.0f;        // padded query rows: any finite value
    else                v = rpb[rel[r * NTOK + c] * NH + h];
    bias_att[i] = v;
  }
}

// col-split 64x32(x256) per-wave GEMM: wave w computes output cols [32w, 32w+32).
// A from swizzled sx; B^T = weight rows (bf16 row-major, read via L2); bias init.
// Weight fragments double-buffered; A-fragment shared across both col-tiles.
__device__ __forceinline__ void gemm32(const char* sxc, const short* __restrict__ wg,
                                       const float* __restrict__ bias,
                                       f32x4 acc[4][2], int w, int lr, int lg) {
  bf16x8 bfr[2][8];
  {
    const short* wr0 = wg + (w * 32 + lr) * CDIM + lg * 8;
    const short* wr1 = wg + (w * 32 + 16 + lr) * CDIM + lg * 8;
    #pragma unroll
    for (int k = 0; k < 8; ++k) bfr[0][k] = *(const bf16x8*)(wr0 + k * 32);
    #pragma unroll
    for (int k = 0; k < 8; ++k) bfr[1][k] = *(const bf16x8*)(wr1 + k * 32);
  }
  const float bv0 = bias[w * 32 + lr];
  const float bv1 = bias[w * 32 + 16 + lr];
  #pragma unroll
  for (int rt = 0; rt < 4; ++rt) {
    f32x4 a0; a0[0] = bv0; a0[1] = bv0; a0[2] = bv0; a0[3] = bv0;
    f32x4 a1; a1[0] = bv1; a1[1] = bv1; a1[2] = bv1; a1[3] = bv1;
    #pragma unroll
    for (int k = 0; k < 8; ++k) {
      const bf16x8 af = *(const bf16x8*)(sxc + sx_b(rt * 16 + lr, k * 32 + lg * 8));
      a0 = __builtin_amdgcn_mfma_f32_16x16x32_bf16(af, bfr[0][k], a0, 0, 0, 0);
      a1 = __builtin_amdgcn_mfma_f32_16x16x32_bf16(af, bfr[1][k], a1, 0, 0, 0);
    }
    acc[rt][0] = a0;
    acc[rt][1] = a1;
  }
}

__global__ __launch_bounds__(512, 4)
void fused_attn(const float* __restrict__ x1, const float* __restrict__ x2,
                const short* __restrict__ wqkv, const float* __restrict__ bias_s,
                const short* __restrict__ wp, const float* __restrict__ proj_b,
                const float* __restrict__ bias_att, float* __restrict__ out) {
  extern __shared__ char ldsc[];
  char* sxc = ldsc;
  char* svc = ldsc + SX_BYTES;
  char* spc = ldsc + SX_BYTES + SV_BYTES;

  const int tid = threadIdx.x;
  const int w = tid >> 6, lane = tid & 63;
  const int lr = lane & 15, lg = lane >> 4;
  const int b = blockIdx.x;
  const int r0 = (w >> 1) * 16;        // wave's query rows
  const int hb = (w & 1) * 4;          // wave's head block

  // ---- stage x1 (f32 -> bf16, rows 49..63 zeroed) ----
  {
    const float* xg = x1 + (size_t)b * NTOK * CDIM;
    #pragma unroll
    for (int it = 0; it < 8; ++it) {
      const int i = tid + it * 512;
      const int row = i >> 6, c4 = i & 63;
      uint2 pkv = make_uint2(0u, 0u);
      if (row < NTOK) {
        const float4 v = *(const float4*)(xg + row * CDIM + c4 * 4);
        pkv.x = pk2(v.x, v.y); pkv.y = pk2(v.z, v.w);
      }
      *(uint2*)(sxc + sx_b(row, c4 * 4)) = pkv;
    }
  }
  __syncthreads();

  f32x4 acc[4][2];

  // ---- Q = x1 @ Wq^T (pre-scaled) ----
  gemm32(sxc, wqkv, bias_s, acc, w, lr, lg);
  __syncthreads();                       // all waves done reading x1
  #pragma unroll
  for (int rt = 0; rt < 4; ++rt)
    #pragma unroll
    for (int ct = 0; ct < 2; ++ct)
      #pragma unroll
      for (int r = 0; r < 4; ++r)
        *(short*)(sxc + sx_b(rt * 16 + lg * 4 + r, w * 32 + ct * 16 + lr)) =
            (short)f2bf_u(acc[rt][ct][r]);
  __syncthreads();

  // per-wave Q A-fragments: rows r0..r0+15, heads hb..hb+3
  bf16x8 qa[4];
  #pragma unroll
  for (int hh = 0; hh < 4; ++hh)
    qa[hh] = *(const bf16x8*)(sxc + sx_b(r0 + lr, (hb + hh) * 32 + lg * 8));
  __syncthreads();                       // everyone grabbed Q before overwrite

  // ---- stage x2 ----
  {
    const float* xg = x2 + (size_t)b * NTOK * CDIM;
    #pragma unroll
    for (int it = 0; it < 8; ++it) {
      const int i = tid + it * 512;
      const int row = i >> 6, c4 = i & 63;
      uint2 pkv = make_uint2(0u, 0u);
      if (row < NTOK) {
        const float4 v = *(const float4*)(xg + row * CDIM + c4 * 4);
        pkv.x = pk2(v.x, v.y); pkv.y = pk2(v.z, v.w);
      }
      *(uint2*)(sxc + sx_b(row, c4 * 4)) = pkv;
    }
  }
  __syncthreads();

  // ---- V = x2 @ Wv^T, stored transposed: sv[feature][token] ----
  gemm32(sxc, wqkv + 512 * CDIM, bias_s + 512, acc, w, lr, lg);
  #pragma unroll
  for (int rt = 0; rt < 4; ++rt)
    #pragma unroll
    for (int ct = 0; ct < 2; ++ct) {
      uint2 pkv = make_uint2(pk2(acc[rt][ct][0], acc[rt][ct][1]),
                             pk2(acc[rt][ct][2], acc[rt][ct][3]));
      *(uint2*)(svc + sv_b(w * 32 + ct * 16 + lr, rt * 16 + lg * 4)) = pkv;
    }

  // ---- K = x2 @ Wk^T (x2 still intact) ----
  gemm32(sxc, wqkv + 256 * CDIM, bias_s + 256, acc, w, lr, lg);
  __syncthreads();                       // all reads of x2 done
  #pragma unroll
  for (int rt = 0; rt < 4; ++rt)
    #pragma unroll
    for (int ct = 0; ct < 2; ++ct)
      #pragma unroll
      for (int r = 0; r < 4; ++r)
        *(short*)(sxc + sx_b(rt * 16 + lg * 4 + r, w * 32 + ct * 16 + lr)) =
            (short)f2bf_u(acc[rt][ct][r]);
  __syncthreads();                       // K and V^T visible

  // ---- attention: wave w -> query rows r0..r0+15, heads hb..hb+3 (barrier-free) ----
  f32x4 oacc[4][2];
  #pragma unroll
  for (int hh = 0; hh < 4; ++hh)
    #pragma unroll
    for (int jt = 0; jt < 2; ++jt) {
      oacc[hh][jt][0] = 0; oacc[hh][jt][1] = 0; oacc[hh][jt][2] = 0; oacc[hh][jt][3] = 0;
    }

  #pragma unroll
  for (int hh = 0; hh < 4; ++hh) {
    const int h = hb + hh;
    const float* bh = bias_att + h * NP * NP + r0 * NP;
    f32x4 s[4];
    #pragma unroll
    for (int ct = 0; ct < 4; ++ct) {
      f32x4 sb;
      #pragma unroll
      for (int r = 0; r < 4; ++r) sb[r] = bh[(lg * 4 + r) * NP + ct * 16 + lr];
      const bf16x8 kb = *(const bf16x8*)(sxc + sx_b(ct * 16 + lr, h * 32 + lg * 8));
      s[ct] = __builtin_amdgcn_mfma_f32_16x16x32_bf16(qa[hh], kb, sb, 0, 0, 0);
    }
    // row softmax: row = r0 + lg*4 + r; cols spread over 16 lanes (lr) x 4 ct
    float mx[4], si[4];
    #pragma unroll
    for (int r = 0; r < 4; ++r) {
      float m = fmaxf(fmaxf(s[0][r], s[1][r]), fmaxf(s[2][r], s[3][r]));
      m = fmaxf(m, __shfl_xor(m, 1, 64));
      m = fmaxf(m, __shfl_xor(m, 2, 64));
      m = fmaxf(m, __shfl_xor(m, 4, 64));
      m = fmaxf(m, __shfl_xor(m, 8, 64));
      mx[r] = m;
    }
    #pragma unroll
    for (int ct = 0; ct < 4; ++ct)
      #pragma unroll
      for (int r = 0; r < 4; ++r)
        s[ct][r] = __expf(s[ct][r] - mx[r]);
    #pragma unroll
    for (int r = 0; r < 4; ++r) {
      float t = s[0][r] + s[1][r] + s[2][r] + s[3][r];
      t += __shfl_xor(t, 1, 64);
      t += __shfl_xor(t, 2, 64);
      t += __shfl_xor(t, 4, 64);
      t += __shfl_xor(t, 8, 64);
      si[r] = __builtin_amdgcn_rcpf(t);
    }
    #pragma unroll
    for (int ct = 0; ct < 4; ++ct)
      #pragma unroll
      for (int r = 0; r < 4; ++r)
        *(short*)(spc + sp_b(w, lg * 4 + r, ct * 16 + lr)) =
            (short)f2bf_u(s[ct][r] * si[r]);
    // PV: rows r0.., cols h*32 + jt*16
    #pragma unroll
    for (int kk = 0; kk < 2; ++kk) {
      const bf16x8 pa = *(const bf16x8*)(spc + sp_b(w, lr, kk * 32 + lg * 8));
      #pragma unroll
      for (int jt = 0; jt < 2; ++jt) {
        const bf16x8 vb = *(const bf16x8*)(svc + sv_b(h * 32 + jt * 16 + lr, kk * 32 + lg * 8));
        oacc[hh][jt] = __builtin_amdgcn_mfma_f32_16x16x32_bf16(pa, vb, oacc[hh][jt], 0, 0, 0);
      }
    }
  }

  // ---- O -> sx (over K, dead now), then proj ----
  __syncthreads();                       // all waves done reading K / V^T
  #pragma unroll
  for (int hh = 0; hh < 4; ++hh)
    #pragma unroll
    for (int jt = 0; jt < 2; ++jt)
      #pragma unroll
      for (int r = 0; r < 4; ++r)
        *(short*)(sxc + sx_b(r0 + lg * 4 + r, (hb + hh) * 32 + jt * 16 + lr)) =
            (short)f2bf_u(oacc[hh][jt][r]);
  __syncthreads();

  gemm32(sxc, wp, proj_b, acc, w, lr, lg);

  // ---- out via f32 LDS staging (reuse sv region), two 128-col halves ----
  float* og = out + (size_t)b * NTOK * CDIM;
  #pragma unroll
  for (int half = 0; half < 2; ++half) {
    if ((w >> 2) == half) {
      const int wc = (w & 3) * 32;       // col within half
      #pragma unroll
      for (int rt = 0; rt < 4; ++rt)
        #pragma unroll
        for (int ct = 0; ct < 2; ++ct)
          #pragma unroll
          for (int r = 0; r < 4; ++r)
            *(float*)(svc + so_b(rt * 16 + lg * 4 + r, wc + ct * 16 + lr)) = acc[rt][ct][r];
    }
    __syncthreads();
    for (int i = tid; i < NTOK * 32; i += 512) {
      const int row = i >> 5, c4 = i & 31;
      const float4 v = *(const float4*)(svc + so_b(row, c4 * 4));
      *(float4*)(og + row * CDIM + half * 128 + c4 * 4) = v;
    }
    __syncthreads();
  }
}

extern "C" void kernel_launch(void* const* d_in, const int* in_sizes, int n_in,
                              void* d_out, int out_size, void* d_ws, size_t ws_size,
                              hipStream_t stream) {
  const float* x1     = (const float*)d_in[0];
  const float* x2     = (const float*)d_in[1];
  const float* qkv_w  = (const float*)d_in[2];
  const float* qkv_b  = (const float*)d_in[3];
  const float* proj_w = (const float*)d_in[4];
  const float* proj_b = (const float*)d_in[5];
  const float* rpb    = (const float*)d_in[6];
  const int*   rel    = (const int*)d_in[7];

  char* ws = (char*)d_ws;
  short* wqkv     = (short*)ws;                                   // 768*256 bf16
  short* wp       = (short*)(ws + 768 * 256 * 2);                 // 256*256 bf16
  float* bias_s   = (float*)(ws + 768 * 256 * 2 + 256 * 256 * 2); // 768 f32
  float* bias_att = (float*)(ws + 768 * 256 * 2 + 256 * 256 * 2 + 768 * 4); // 8*64*64 f32

  const int prep_total = 768 * 256 + 256 * 256 + 768 + NH * NP * NP;
  prep_kernel<<<(prep_total + 255) / 256, 256, 0, stream>>>(
      qkv_w, qkv_b, proj_w, rpb, rel, wqkv, wp, bias_s, bias_att);

  const int Bn = in_sizes[0] / (NTOK * CDIM);
  const size_t shmem = SX_BYTES + SV_BYTES + SP_BYTES;            // 81920
  (void)hipFuncSetAttribute((const void*)fused_attn,
                            hipFuncAttributeMaxDynamicSharedMemorySize, (int)shmem);
  fused_attn<<<Bn, 512, shmem, stream>>>(x1, x2, wqkv, bias_s, wp, proj_b, bias_att,
                                         (float*)d_out);
}

// Round 3
// 307.175 us; speedup vs baseline: 1.4599x; 1.1702x over previous
//
#include <hip/hip_runtime.h>
#include <hip/hip_bf16.h>

#define NTOK 49
#define NP 64
#define CDIM 256
#define NH 8
#define SCALE 0.17677669529663687f

// LDS (all XOR-16 swizzled, exact fit 2 blocks/CU):
//   sx : [64][256] bf16  (x1 -> Q in place -> x2 -> K in place -> O)   32768 B
//   sv : [256][64] bf16  V^T feature-major                              32768 B
//   sp : 8 waves x [16][64] bf16  P (wave-private)                      16384 B
#define SX_BYTES 32768
#define SV_BYTES 32768
#define SP_BYTES 16384

using f32x4  = __attribute__((ext_vector_type(4))) float;
using bf16x8 = __attribute__((ext_vector_type(8))) short;

__device__ __forceinline__ unsigned f2bf_u(float f) {
  union { float f; unsigned u; } c; c.f = f;
  return (c.u + 0x7fffu + ((c.u >> 16) & 1u)) >> 16;   // RNE
}
__device__ __forceinline__ unsigned pk2(float a, float b) {
  return f2bf_u(a) | (f2bf_u(b) << 16);
}

// byte-offset helpers with XOR-16 swizzle (row-bit into 16B-slot bit)
__device__ __forceinline__ int sx_b(int row, int col) {   // bf16 [64][256]
  return (row * 512 + col * 2) ^ ((row & 7) << 4);
}
__device__ __forceinline__ int sv_b(int feat, int tok) {  // bf16 [256][64]
  return (feat * 128 + tok * 2) ^ ((feat & 7) << 4);
}
__device__ __forceinline__ int sp_b(int w, int row, int key) { // bf16 8x[16][64]
  return w * 2048 + ((row * 128 + key * 2) ^ ((row & 7) << 4));
}
__device__ __forceinline__ int so_b(int row, int col) {   // f32 [64][128] (out stage)
  return (row * 512 + col * 4) ^ ((row & 7) << 4);
}

// ---------------- prep: bf16 weights (scale folded into Wq), attention bias table
__global__ void prep_kernel(const float* __restrict__ qkv_w, const float* __restrict__ qkv_b,
                            const float* __restrict__ proj_w,
                            const float* __restrict__ rpb, const int* __restrict__ rel,
                            short* __restrict__ wqkv, short* __restrict__ wp,
                            float* __restrict__ bias_s, float* __restrict__ bias_att) {
  int i = blockIdx.x * 256 + threadIdx.x;
  if (i < 768 * 256) {
    int j = i >> 8;
    float v = qkv_w[i] * (j < 256 ? SCALE : 1.0f);
    wqkv[i] = (short)f2bf_u(v);
    return;
  }
  i -= 768 * 256;
  if (i < 256 * 256) { wp[i] = (short)f2bf_u(proj_w[i]); return; }
  i -= 256 * 256;
  if (i < 768) { bias_s[i] = qkv_b[i] * (i < 256 ? SCALE : 1.0f); return; }
  i -= 768;
  if (i < NH * NP * NP) {
    int h = i >> 12, rem = i & 4095, r = rem >> 6, c = rem & 63;
    float v;
    if (c >= NTOK)      v = -1e30f;      // mask padded key columns
    else if (r >= NTOK) v = 0.0f;        // padded query rows: any finite value
    else                v = rpb[rel[r * NTOK + c] * NH + h];
    bias_att[i] = v;
  }
}

// col-split 64x32(x256) per-wave GEMM: wave w computes output cols [32w, 32w+32).
// A from swizzled sx; B^T = weight rows (bf16 row-major, via L2); bias init.
// k-OUTER order: only 2 weight fragments (8 VGPRs) live at a time (reg-pressure fix).
__device__ __forceinline__ void gemm32(const char* sxc, const short* __restrict__ wg,
                                       const float* __restrict__ bias,
                                       f32x4 acc[4][2], int w, int lr, int lg) {
  const short* wr0 = wg + (w * 32 + lr) * CDIM + lg * 8;
  const short* wr1 = wg + (w * 32 + 16 + lr) * CDIM + lg * 8;
  const float bv0 = bias[w * 32 + lr];
  const float bv1 = bias[w * 32 + 16 + lr];
  #pragma unroll
  for (int rt = 0; rt < 4; ++rt) {
    #pragma unroll
    for (int r = 0; r < 4; ++r) { acc[rt][0][r] = bv0; acc[rt][1][r] = bv1; }
  }
  #pragma unroll
  for (int k = 0; k < 8; ++k) {
    const bf16x8 b0 = *(const bf16x8*)(wr0 + k * 32);
    const bf16x8 b1 = *(const bf16x8*)(wr1 + k * 32);
    #pragma unroll
    for (int rt = 0; rt < 4; ++rt) {
      const bf16x8 af = *(const bf16x8*)(sxc + sx_b(rt * 16 + lr, k * 32 + lg * 8));
      acc[rt][0] = __builtin_amdgcn_mfma_f32_16x16x32_bf16(af, b0, acc[rt][0], 0, 0, 0);
      acc[rt][1] = __builtin_amdgcn_mfma_f32_16x16x32_bf16(af, b1, acc[rt][1], 0, 0, 0);
    }
  }
}

__global__ __launch_bounds__(512) __attribute__((amdgpu_waves_per_eu(4, 4)))
void fused_attn(const float* __restrict__ x1, const float* __restrict__ x2,
                const short* __restrict__ wqkv, const float* __restrict__ bias_s,
                const short* __restrict__ wp, const float* __restrict__ proj_b,
                const float* __restrict__ bias_att, float* __restrict__ out) {
  extern __shared__ char ldsc[];
  char* sxc = ldsc;
  char* svc = ldsc + SX_BYTES;
  char* spc = ldsc + SX_BYTES + SV_BYTES;

  const int tid = threadIdx.x;
  const int w = tid >> 6, lane = tid & 63;
  const int lr = lane & 15, lg = lane >> 4;
  const int b = blockIdx.x;
  const int r0 = (w >> 1) * 16;        // wave's query rows
  const int hb = (w & 1) * 4;          // wave's head block

  // ---- stage x1 (f32 -> bf16, rows 49..63 zeroed) ----
  {
    const float* xg = x1 + (size_t)b * NTOK * CDIM;
    #pragma unroll
    for (int it = 0; it < 8; ++it) {
      const int i = tid + it * 512;
      const int row = i >> 6, c4 = i & 63;
      uint2 pkv = make_uint2(0u, 0u);
      if (row < NTOK) {
        const float4 v = *(const float4*)(xg + row * CDIM + c4 * 4);
        pkv.x = pk2(v.x, v.y); pkv.y = pk2(v.z, v.w);
      }
      *(uint2*)(sxc + sx_b(row, c4 * 4)) = pkv;
    }
  }
  __syncthreads();

  f32x4 acc[4][2];

  // ---- Q = x1 @ Wq^T (pre-scaled) ----
  gemm32(sxc, wqkv, bias_s, acc, w, lr, lg);
  __syncthreads();                       // all waves done reading x1
  #pragma unroll
  for (int rt = 0; rt < 4; ++rt)
    #pragma unroll
    for (int ct = 0; ct < 2; ++ct)
      #pragma unroll
      for (int r = 0; r < 4; ++r)
        *(short*)(sxc + sx_b(rt * 16 + lg * 4 + r, w * 32 + ct * 16 + lr)) =
            (short)f2bf_u(acc[rt][ct][r]);
  __syncthreads();

  // per-wave Q A-fragments: rows r0..r0+15, heads hb..hb+3
  bf16x8 qa[4];
  #pragma unroll
  for (int hh = 0; hh < 4; ++hh)
    qa[hh] = *(const bf16x8*)(sxc + sx_b(r0 + lr, (hb + hh) * 32 + lg * 8));
  __syncthreads();                       // everyone grabbed Q before overwrite

  // ---- stage x2 ----
  {
    const float* xg = x2 + (size_t)b * NTOK * CDIM;
    #pragma unroll
    for (int it = 0; it < 8; ++it) {
      const int i = tid + it * 512;
      const int row = i >> 6, c4 = i & 63;
      uint2 pkv = make_uint2(0u, 0u);
      if (row < NTOK) {
        const float4 v = *(const float4*)(xg + row * CDIM + c4 * 4);
        pkv.x = pk2(v.x, v.y); pkv.y = pk2(v.z, v.w);
      }
      *(uint2*)(sxc + sx_b(row, c4 * 4)) = pkv;
    }
  }
  __syncthreads();

  // ---- V = x2 @ Wv^T, stored transposed: sv[feature][token] ----
  gemm32(sxc, wqkv + 512 * CDIM, bias_s + 512, acc, w, lr, lg);
  #pragma unroll
  for (int rt = 0; rt < 4; ++rt)
    #pragma unroll
    for (int ct = 0; ct < 2; ++ct) {
      uint2 pkv = make_uint2(pk2(acc[rt][ct][0], acc[rt][ct][1]),
                             pk2(acc[rt][ct][2], acc[rt][ct][3]));
      *(uint2*)(svc + sv_b(w * 32 + ct * 16 + lr, rt * 16 + lg * 4)) = pkv;
    }

  // ---- K = x2 @ Wk^T (x2 still intact) ----
  gemm32(sxc, wqkv + 256 * CDIM, bias_s + 256, acc, w, lr, lg);
  __syncthreads();                       // all reads of x2 done
  #pragma unroll
  for (int rt = 0; rt < 4; ++rt)
    #pragma unroll
    for (int ct = 0; ct < 2; ++ct)
      #pragma unroll
      for (int r = 0; r < 4; ++r)
        *(short*)(sxc + sx_b(rt * 16 + lg * 4 + r, w * 32 + ct * 16 + lr)) =
            (short)f2bf_u(acc[rt][ct][r]);
  __syncthreads();                       // K and V^T visible

  // ---- attention: wave w -> query rows r0..r0+15, heads hb..hb+3 (barrier-free) ----
  f32x4 oacc[4][2];
  #pragma unroll
  for (int hh = 0; hh < 4; ++hh)
    #pragma unroll
    for (int jt = 0; jt < 2; ++jt) {
      oacc[hh][jt][0] = 0; oacc[hh][jt][1] = 0; oacc[hh][jt][2] = 0; oacc[hh][jt][3] = 0;
    }

  #pragma unroll
  for (int hh = 0; hh < 4; ++hh) {
    const int h = hb + hh;
    const float* bh = bias_att + h * NP * NP + r0 * NP;
    f32x4 s[4];
    #pragma unroll
    for (int ct = 0; ct < 4; ++ct) {
      f32x4 sb;
      #pragma unroll
      for (int r = 0; r < 4; ++r) sb[r] = bh[(lg * 4 + r) * NP + ct * 16 + lr];
      const bf16x8 kb = *(const bf16x8*)(sxc + sx_b(ct * 16 + lr, h * 32 + lg * 8));
      s[ct] = __builtin_amdgcn_mfma_f32_16x16x32_bf16(qa[hh], kb, sb, 0, 0, 0);
    }
    // row softmax: row = r0 + lg*4 + r; cols spread over 16 lanes (lr) x 4 ct
    float mx[4], si[4];
    #pragma unroll
    for (int r = 0; r < 4; ++r) {
      float m = fmaxf(fmaxf(s[0][r], s[1][r]), fmaxf(s[2][r], s[3][r]));
      m = fmaxf(m, __shfl_xor(m, 1, 64));
      m = fmaxf(m, __shfl_xor(m, 2, 64));
      m = fmaxf(m, __shfl_xor(m, 4, 64));
      m = fmaxf(m, __shfl_xor(m, 8, 64));
      mx[r] = m;
    }
    #pragma unroll
    for (int ct = 0; ct < 4; ++ct)
      #pragma unroll
      for (int r = 0; r < 4; ++r)
        s[ct][r] = __expf(s[ct][r] - mx[r]);
    #pragma unroll
    for (int r = 0; r < 4; ++r) {
      float t = s[0][r] + s[1][r] + s[2][r] + s[3][r];
      t += __shfl_xor(t, 1, 64);
      t += __shfl_xor(t, 2, 64);
      t += __shfl_xor(t, 4, 64);
      t += __shfl_xor(t, 8, 64);
      si[r] = __builtin_amdgcn_rcpf(t);
    }
    #pragma unroll
    for (int ct = 0; ct < 4; ++ct)
      #pragma unroll
      for (int r = 0; r < 4; ++r)
        *(short*)(spc + sp_b(w, lg * 4 + r, ct * 16 + lr)) =
            (short)f2bf_u(s[ct][r] * si[r]);
    // PV: rows r0.., cols h*32 + jt*16
    #pragma unroll
    for (int kk = 0; kk < 2; ++kk) {
      const bf16x8 pa = *(const bf16x8*)(spc + sp_b(w, lr, kk * 32 + lg * 8));
      #pragma unroll
      for (int jt = 0; jt < 2; ++jt) {
        const bf16x8 vb = *(const bf16x8*)(svc + sv_b(h * 32 + jt * 16 + lr, kk * 32 + lg * 8));
        oacc[hh][jt] = __builtin_amdgcn_mfma_f32_16x16x32_bf16(pa, vb, oacc[hh][jt], 0, 0, 0);
      }
    }
  }

  // ---- O -> sx (over K, dead now), then proj ----
  __syncthreads();                       // all waves done reading K / V^T
  #pragma unroll
  for (int hh = 0; hh < 4; ++hh)
    #pragma unroll
    for (int jt = 0; jt < 2; ++jt)
      #pragma unroll
      for (int r = 0; r < 4; ++r)
        *(short*)(sxc + sx_b(r0 + lg * 4 + r, (hb + hh) * 32 + jt * 16 + lr)) =
            (short)f2bf_u(oacc[hh][jt][r]);
  __syncthreads();

  gemm32(sxc, wp, proj_b, acc, w, lr, lg);

  // ---- out via f32 LDS staging (reuse sv region), two 128-col halves ----
  float* og = out + (size_t)b * NTOK * CDIM;
  #pragma unroll
  for (int half = 0; half < 2; ++half) {
    if ((w >> 2) == half) {
      const int wc = (w & 3) * 32;       // col within half
      #pragma unroll
      for (int rt = 0; rt < 4; ++rt)
        #pragma unroll
        for (int ct = 0; ct < 2; ++ct)
          #pragma unroll
          for (int r = 0; r < 4; ++r)
            *(float*)(svc + so_b(rt * 16 + lg * 4 + r, wc + ct * 16 + lr)) = acc[rt][ct][r];
    }
    __syncthreads();
    for (int i = tid; i < NTOK * 32; i += 512) {
      const int row = i >> 5, c4 = i & 31;
      const float4 v = *(const float4*)(svc + so_b(row, c4 * 4));
      *(float4*)(og + row * CDIM + half * 128 + c4 * 4) = v;
    }
    __syncthreads();
  }
}

extern "C" void kernel_launch(void* const* d_in, const int* in_sizes, int n_in,
                              void* d_out, int out_size, void* d_ws, size_t ws_size,
                              hipStream_t stream) {
  const float* x1     = (const float*)d_in[0];
  const float* x2     = (const float*)d_in[1];
  const float* qkv_w  = (const float*)d_in[2];
  const float* qkv_b  = (const float*)d_in[3];
  const float* proj_w = (const float*)d_in[4];
  const float* proj_b = (const float*)d_in[5];
  const float* rpb    = (const float*)d_in[6];
  const int*   rel    = (const int*)d_in[7];

  char* ws = (char*)d_ws;
  short* wqkv     = (short*)ws;                                   // 768*256 bf16
  short* wp       = (short*)(ws + 768 * 256 * 2);                 // 256*256 bf16
  float* bias_s   = (float*)(ws + 768 * 256 * 2 + 256 * 256 * 2); // 768 f32
  float* bias_att = (float*)(ws + 768 * 256 * 2 + 256 * 256 * 2 + 768 * 4); // 8*64*64 f32

  const int prep_total = 768 * 256 + 256 * 256 + 768 + NH * NP * NP;
  prep_kernel<<<(prep_total + 255) / 256, 256, 0, stream>>>(
      qkv_w, qkv_b, proj_w, rpb, rel, wqkv, wp, bias_s, bias_att);

  const int Bn = in_sizes[0] / (NTOK * CDIM);
  const size_t shmem = SX_BYTES + SV_BYTES + SP_BYTES;            // 81920
  (void)hipFuncSetAttribute((const void*)fused_attn,
                            hipFuncAttributeMaxDynamicSharedMemorySize, (int)shmem);
  fused_attn<<<Bn, 512, shmem, stream>>>(x1, x2, wqkv, bias_s, wp, proj_b, bias_att,
                                         (float*)d_out);
}

// Round 4
// 290.797 us; speedup vs baseline: 1.5421x; 1.0563x over previous
//
#include <hip/hip_runtime.h>
#include <hip/hip_bf16.h>

#define NTOK 49
#define NP 64
#define CDIM 256
#define NH 8
#define SCALE 0.17677669529663687f

// fused-path LDS
#define SX_BYTES 32768
#define SV_BYTES 32768
#define SP_BYTES 16384

using f32x4  = __attribute__((ext_vector_type(4))) float;
using bf16x8 = __attribute__((ext_vector_type(8))) short;

__device__ __forceinline__ unsigned f2bf_u(float f) {
  union { float f; unsigned u; } c; c.f = f;
  return (c.u + 0x7fffu + ((c.u >> 16) & 1u)) >> 16;   // RNE
}
__device__ __forceinline__ unsigned pk2(float a, float b) {
  return f2bf_u(a) | (f2bf_u(b) << 16);
}

// byte-offset helpers with XOR-16 swizzle (row-bit into 16B-slot bit)
__device__ __forceinline__ int sx_b(int row, int col) {   // bf16 [64][256] image
  return (row * 512 + col * 2) ^ ((row & 7) << 4);
}
__device__ __forceinline__ int sv_b(int feat, int tok) {  // bf16 [256][64] image
  return (feat * 128 + tok * 2) ^ ((feat & 7) << 4);
}
__device__ __forceinline__ int sp_b(int w, int row, int key) { // bf16 per-wave [16][64]
  return w * 2048 + ((row * 128 + key * 2) ^ ((row & 7) << 4));
}
__device__ __forceinline__ int so_b(int row, int col) {   // f32 [64][128] (fused out stage)
  return (row * 512 + col * 4) ^ ((row & 7) << 4);
}

// ---------------- prep: bf16 weights (scale folded into Wq), attention bias table
__global__ void prep_kernel(const float* __restrict__ qkv_w, const float* __restrict__ qkv_b,
                            const float* __restrict__ proj_w,
                            const float* __restrict__ rpb, const int* __restrict__ rel,
                            short* __restrict__ wqkv, short* __restrict__ wp,
                            float* __restrict__ bias_s, float* __restrict__ bias_att) {
  int i = blockIdx.x * 256 + threadIdx.x;
  if (i < 768 * 256) {
    int j = i >> 8;
    float v = qkv_w[i] * (j < 256 ? SCALE : 1.0f);
    wqkv[i] = (short)f2bf_u(v);
    return;
  }
  i -= 768 * 256;
  if (i < 256 * 256) { wp[i] = (short)f2bf_u(proj_w[i]); return; }
  i -= 256 * 256;
  if (i < 768) { bias_s[i] = qkv_b[i] * (i < 256 ? SCALE : 1.0f); return; }
  i -= 768;
  if (i < NH * NP * NP) {
    int h = i >> 12, rem = i & 4095, r = rem >> 6, c = rem & 63;
    float v;
    if (c >= NTOK)      v = -1e30f;      // mask padded key columns
    else if (r >= NTOK) v = 0.0f;        // padded query rows: any finite value
    else                v = rpb[rel[r * NTOK + c] * NH + h];
    bias_att[i] = v;
  }
}

// col-split 64x32(x256) per-wave GEMM, k-outer (low reg pressure)
__device__ __forceinline__ void gemm32(const char* sxc, const short* __restrict__ wg,
                                       const float* __restrict__ bias,
                                       f32x4 acc[4][2], int w, int lr, int lg) {
  const short* wr0 = wg + (w * 32 + lr) * CDIM + lg * 8;
  const short* wr1 = wg + (w * 32 + 16 + lr) * CDIM + lg * 8;
  const float bv0 = bias[w * 32 + lr];
  const float bv1 = bias[w * 32 + 16 + lr];
  #pragma unroll
  for (int rt = 0; rt < 4; ++rt) {
    #pragma unroll
    for (int r = 0; r < 4; ++r) { acc[rt][0][r] = bv0; acc[rt][1][r] = bv1; }
  }
  #pragma unroll
  for (int k = 0; k < 8; ++k) {
    const bf16x8 b0 = *(const bf16x8*)(wr0 + k * 32);
    const bf16x8 b1 = *(const bf16x8*)(wr1 + k * 32);
    #pragma unroll
    for (int rt = 0; rt < 4; ++rt) {
      const bf16x8 af = *(const bf16x8*)(sxc + sx_b(rt * 16 + lr, k * 32 + lg * 8));
      acc[rt][0] = __builtin_amdgcn_mfma_f32_16x16x32_bf16(af, b0, acc[rt][0], 0, 0, 0);
      acc[rt][1] = __builtin_amdgcn_mfma_f32_16x16x32_bf16(af, b1, acc[rt][1], 0, 0, 0);
    }
  }
}

// stage one batch of x (f32->bf16, rows >=49 zeroed) into sx image; NT threads
template <int NT>
__device__ __forceinline__ void stage_x(char* sxc, const float* __restrict__ xg, int tid) {
  #pragma unroll
  for (int it = 0; it < 4096 / NT; ++it) {
    const int i = tid + it * NT;
    const int row = i >> 6, c4 = i & 63;
    uint2 pkv = make_uint2(0u, 0u);
    if (row < NTOK) {
      const float4 v = *(const float4*)(xg + row * CDIM + c4 * 4);
      pkv.x = pk2(v.x, v.y); pkv.y = pk2(v.z, v.w);
    }
    *(uint2*)(sxc + sx_b(row, c4 * 4)) = pkv;
  }
}

// ================= SPLIT PATH =================
// per-batch ws images: q (32KB, sx_b layout) | k (32KB, sx_b) | vt (32KB, sv_b)
#define IMG_STRIDE 98304

__global__ __launch_bounds__(512) __attribute__((amdgpu_waves_per_eu(4, 4)))
void qkv_kernel(const float* __restrict__ x1, const float* __restrict__ x2,
                const short* __restrict__ wqkv, const float* __restrict__ bias_s,
                char* __restrict__ img) {
  extern __shared__ char ldsc[];
  char* sxc = ldsc;            // 32 KB staging
  char* stc = ldsc + 32768;    // 32 KB bounce

  const int tid = threadIdx.x;
  const int w = tid >> 6, lane = tid & 63;
  const int lr = lane & 15, lg = lane >> 4;
  const int b = blockIdx.x;
  char* wsb = img + (size_t)b * IMG_STRIDE;

  f32x4 acc[4][2];

  // P1: stage x1
  stage_x<512>(sxc, x1 + (size_t)b * NTOK * CDIM, tid);
  __syncthreads();

  // P2: Q gemm -> st (sx_b image)
  gemm32(sxc, wqkv, bias_s, acc, w, lr, lg);
  #pragma unroll
  for (int rt = 0; rt < 4; ++rt)
    #pragma unroll
    for (int ct = 0; ct < 2; ++ct)
      #pragma unroll
      for (int r = 0; r < 4; ++r)
        *(short*)(stc + sx_b(rt * 16 + lg * 4 + r, w * 32 + ct * 16 + lr)) =
            (short)f2bf_u(acc[rt][ct][r]);
  __syncthreads();

  // P3: copy st -> ws_q ; stage x2 -> sx
  #pragma unroll
  for (int it = 0; it < 4; ++it) {
    const int i = tid + it * 512;
    *(float4*)(wsb + i * 16) = *(const float4*)(stc + i * 16);
  }
  stage_x<512>(sxc, x2 + (size_t)b * NTOK * CDIM, tid);
  __syncthreads();

  // P4: V gemm -> st (sv_b V^T image)
  gemm32(sxc, wqkv + 512 * CDIM, bias_s + 512, acc, w, lr, lg);
  #pragma unroll
  for (int rt = 0; rt < 4; ++rt)
    #pragma unroll
    for (int ct = 0; ct < 2; ++ct) {
      uint2 pkv = make_uint2(pk2(acc[rt][ct][0], acc[rt][ct][1]),
                             pk2(acc[rt][ct][2], acc[rt][ct][3]));
      *(uint2*)(stc + sv_b(w * 32 + ct * 16 + lr, rt * 16 + lg * 4)) = pkv;
    }
  __syncthreads();

  // P5: copy st -> ws_vt ; K gemm (x2 still in sx)
  #pragma unroll
  for (int it = 0; it < 4; ++it) {
    const int i = tid + it * 512;
    *(float4*)(wsb + 65536 + i * 16) = *(const float4*)(stc + i * 16);
  }
  gemm32(sxc, wqkv + 256 * CDIM, bias_s + 256, acc, w, lr, lg);
  __syncthreads();

  // P6: K -> st (sx_b image)
  #pragma unroll
  for (int rt = 0; rt < 4; ++rt)
    #pragma unroll
    for (int ct = 0; ct < 2; ++ct)
      #pragma unroll
      for (int r = 0; r < 4; ++r)
        *(short*)(stc + sx_b(rt * 16 + lg * 4 + r, w * 32 + ct * 16 + lr)) =
            (short)f2bf_u(acc[rt][ct][r]);
  __syncthreads();

  // P7: copy st -> ws_k
  #pragma unroll
  for (int it = 0; it < 4; ++it) {
    const int i = tid + it * 512;
    *(float4*)(wsb + 32768 + i * 16) = *(const float4*)(stc + i * 16);
  }
}

__global__ __launch_bounds__(256) __attribute__((amdgpu_waves_per_eu(4, 4)))
void attnproj_kernel(const char* __restrict__ img, const short* __restrict__ wp,
                     const float* __restrict__ proj_b, const float* __restrict__ bias_att,
                     float* __restrict__ out) {
  extern __shared__ char ldsc[];
  char* soc = ldsc;            // 32 KB O image (sx_b)
  char* spc = ldsc + 32768;    // 8 KB P (2 KB per wave)

  const int tid = threadIdx.x;
  const int w = tid >> 6, lane = tid & 63;
  const int lr = lane & 15, lg = lane >> 4;
  const int b = blockIdx.x;
  const char* qimg = img + (size_t)b * IMG_STRIDE;
  const char* kimg = qimg + 32768;
  const char* vimg = qimg + 65536;

  // ---- attention: wave w owns heads 2w, 2w+1 over all 64 q-rows ----
  #pragma unroll
  for (int hh = 0; hh < 2; ++hh) {
    const int h = w * 2 + hh;
    bf16x8 kb[4];
    #pragma unroll
    for (int ct = 0; ct < 4; ++ct)
      kb[ct] = *(const bf16x8*)(kimg + sx_b(ct * 16 + lr, h * 32 + lg * 8));
    bf16x8 vb[2][2];
    #pragma unroll
    for (int kk = 0; kk < 2; ++kk)
      #pragma unroll
      for (int jt = 0; jt < 2; ++jt)
        vb[kk][jt] = *(const bf16x8*)(vimg + sv_b(h * 32 + jt * 16 + lr, kk * 32 + lg * 8));
    const float* bh = bias_att + h * NP * NP;

    #pragma unroll
    for (int qt = 0; qt < 4; ++qt) {
      const bf16x8 qa = *(const bf16x8*)(qimg + sx_b(qt * 16 + lr, h * 32 + lg * 8));
      f32x4 s[4];
      #pragma unroll
      for (int ct = 0; ct < 4; ++ct) {
        f32x4 sb;
        #pragma unroll
        for (int r = 0; r < 4; ++r) sb[r] = bh[(qt * 16 + lg * 4 + r) * NP + ct * 16 + lr];
        s[ct] = __builtin_amdgcn_mfma_f32_16x16x32_bf16(qa, kb[ct], sb, 0, 0, 0);
      }
      float mx[4], si[4];
      #pragma unroll
      for (int r = 0; r < 4; ++r) {
        float m = fmaxf(fmaxf(s[0][r], s[1][r]), fmaxf(s[2][r], s[3][r]));
        m = fmaxf(m, __shfl_xor(m, 1, 64));
        m = fmaxf(m, __shfl_xor(m, 2, 64));
        m = fmaxf(m, __shfl_xor(m, 4, 64));
        m = fmaxf(m, __shfl_xor(m, 8, 64));
        mx[r] = m;
      }
      #pragma unroll
      for (int ct = 0; ct < 4; ++ct)
        #pragma unroll
        for (int r = 0; r < 4; ++r)
          s[ct][r] = __expf(s[ct][r] - mx[r]);
      #pragma unroll
      for (int r = 0; r < 4; ++r) {
        float t = s[0][r] + s[1][r] + s[2][r] + s[3][r];
        t += __shfl_xor(t, 1, 64);
        t += __shfl_xor(t, 2, 64);
        t += __shfl_xor(t, 4, 64);
        t += __shfl_xor(t, 8, 64);
        si[r] = __builtin_amdgcn_rcpf(t);
      }
      #pragma unroll
      for (int ct = 0; ct < 4; ++ct)
        #pragma unroll
        for (int r = 0; r < 4; ++r)
          *(short*)(spc + sp_b(w, lg * 4 + r, ct * 16 + lr)) =
              (short)f2bf_u(s[ct][r] * si[r]);
      // PV for this qt (wave-local LDS dependency)
      f32x4 oq[2];
      #pragma unroll
      for (int jt = 0; jt < 2; ++jt) { oq[jt][0] = 0; oq[jt][1] = 0; oq[jt][2] = 0; oq[jt][3] = 0; }
      #pragma unroll
      for (int kk = 0; kk < 2; ++kk) {
        const bf16x8 pa = *(const bf16x8*)(spc + sp_b(w, lr, kk * 32 + lg * 8));
        #pragma unroll
        for (int jt = 0; jt < 2; ++jt)
          oq[jt] = __builtin_amdgcn_mfma_f32_16x16x32_bf16(pa, vb[kk][jt], oq[jt], 0, 0, 0);
      }
      #pragma unroll
      for (int jt = 0; jt < 2; ++jt)
        #pragma unroll
        for (int r = 0; r < 4; ++r)
          *(short*)(soc + sx_b(qt * 16 + lg * 4 + r, h * 32 + jt * 16 + lr)) =
              (short)f2bf_u(oq[jt][r]);
    }
  }
  __syncthreads();   // O image complete

  // ---- proj: two 32-col passes per wave, direct f32 stores (64B row segments) ----
  float* og = out + (size_t)b * NTOK * CDIM;
  #pragma unroll
  for (int p = 0; p < 2; ++p) {
    const int c0 = w * 64 + p * 32;
    const short* wr0 = wp + (c0 + lr) * CDIM + lg * 8;
    const short* wr1 = wp + (c0 + 16 + lr) * CDIM + lg * 8;
    const float bv0 = proj_b[c0 + lr];
    const float bv1 = proj_b[c0 + 16 + lr];
    f32x4 acc[4][2];
    #pragma unroll
    for (int rt = 0; rt < 4; ++rt)
      #pragma unroll
      for (int r = 0; r < 4; ++r) { acc[rt][0][r] = bv0; acc[rt][1][r] = bv1; }
    #pragma unroll
    for (int k = 0; k < 8; ++k) {
      const bf16x8 b0 = *(const bf16x8*)(wr0 + k * 32);
      const bf16x8 b1 = *(const bf16x8*)(wr1 + k * 32);
      #pragma unroll
      for (int rt = 0; rt < 4; ++rt) {
        const bf16x8 af = *(const bf16x8*)(soc + sx_b(rt * 16 + lr, k * 32 + lg * 8));
        acc[rt][0] = __builtin_amdgcn_mfma_f32_16x16x32_bf16(af, b0, acc[rt][0], 0, 0, 0);
        acc[rt][1] = __builtin_amdgcn_mfma_f32_16x16x32_bf16(af, b1, acc[rt][1], 0, 0, 0);
      }
    }
    #pragma unroll
    for (int rt = 0; rt < 4; ++rt)
      #pragma unroll
      for (int r = 0; r < 4; ++r) {
        const int row = rt * 16 + lg * 4 + r;
        if (row < NTOK) {
          #pragma unroll
          for (int ct = 0; ct < 2; ++ct)
            og[row * CDIM + c0 + ct * 16 + lr] = acc[rt][ct][r];
        }
      }
  }
}

// ================= FUSED FALLBACK (R3, unchanged) =================
__global__ __launch_bounds__(512) __attribute__((amdgpu_waves_per_eu(4, 4)))
void fused_attn(const float* __restrict__ x1, const float* __restrict__ x2,
                const short* __restrict__ wqkv, const float* __restrict__ bias_s,
                const short* __restrict__ wp, const float* __restrict__ proj_b,
                const float* __restrict__ bias_att, float* __restrict__ out) {
  extern __shared__ char ldsc[];
  char* sxc = ldsc;
  char* svc = ldsc + SX_BYTES;
  char* spc = ldsc + SX_BYTES + SV_BYTES;

  const int tid = threadIdx.x;
  const int w = tid >> 6, lane = tid & 63;
  const int lr = lane & 15, lg = lane >> 4;
  const int b = blockIdx.x;
  const int r0 = (w >> 1) * 16;
  const int hb = (w & 1) * 4;

  stage_x<512>(sxc, x1 + (size_t)b * NTOK * CDIM, tid);
  __syncthreads();

  f32x4 acc[4][2];
  gemm32(sxc, wqkv, bias_s, acc, w, lr, lg);
  __syncthreads();
  #pragma unroll
  for (int rt = 0; rt < 4; ++rt)
    #pragma unroll
    for (int ct = 0; ct < 2; ++ct)
      #pragma unroll
      for (int r = 0; r < 4; ++r)
        *(short*)(sxc + sx_b(rt * 16 + lg * 4 + r, w * 32 + ct * 16 + lr)) =
            (short)f2bf_u(acc[rt][ct][r]);
  __syncthreads();

  bf16x8 qa[4];
  #pragma unroll
  for (int hh = 0; hh < 4; ++hh)
    qa[hh] = *(const bf16x8*)(sxc + sx_b(r0 + lr, (hb + hh) * 32 + lg * 8));
  __syncthreads();

  stage_x<512>(sxc, x2 + (size_t)b * NTOK * CDIM, tid);
  __syncthreads();

  gemm32(sxc, wqkv + 512 * CDIM, bias_s + 512, acc, w, lr, lg);
  #pragma unroll
  for (int rt = 0; rt < 4; ++rt)
    #pragma unroll
    for (int ct = 0; ct < 2; ++ct) {
      uint2 pkv = make_uint2(pk2(acc[rt][ct][0], acc[rt][ct][1]),
                             pk2(acc[rt][ct][2], acc[rt][ct][3]));
      *(uint2*)(svc + sv_b(w * 32 + ct * 16 + lr, rt * 16 + lg * 4)) = pkv;
    }

  gemm32(sxc, wqkv + 256 * CDIM, bias_s + 256, acc, w, lr, lg);
  __syncthreads();
  #pragma unroll
  for (int rt = 0; rt < 4; ++rt)
    #pragma unroll
    for (int ct = 0; ct < 2; ++ct)
      #pragma unroll
      for (int r = 0; r < 4; ++r)
        *(short*)(sxc + sx_b(rt * 16 + lg * 4 + r, w * 32 + ct * 16 + lr)) =
            (short)f2bf_u(acc[rt][ct][r]);
  __syncthreads();

  f32x4 oacc[4][2];
  #pragma unroll
  for (int hh = 0; hh < 4; ++hh)
    #pragma unroll
    for (int jt = 0; jt < 2; ++jt) {
      oacc[hh][jt][0] = 0; oacc[hh][jt][1] = 0; oacc[hh][jt][2] = 0; oacc[hh][jt][3] = 0;
    }

  #pragma unroll
  for (int hh = 0; hh < 4; ++hh) {
    const int h = hb + hh;
    const float* bh = bias_att + h * NP * NP + r0 * NP;
    f32x4 s[4];
    #pragma unroll
    for (int ct = 0; ct < 4; ++ct) {
      f32x4 sb;
      #pragma unroll
      for (int r = 0; r < 4; ++r) sb[r] = bh[(lg * 4 + r) * NP + ct * 16 + lr];
      const bf16x8 kb = *(const bf16x8*)(sxc + sx_b(ct * 16 + lr, h * 32 + lg * 8));
      s[ct] = __builtin_amdgcn_mfma_f32_16x16x32_bf16(qa[hh], kb, sb, 0, 0, 0);
    }
    float mx[4], si[4];
    #pragma unroll
    for (int r = 0; r < 4; ++r) {
      float m = fmaxf(fmaxf(s[0][r], s[1][r]), fmaxf(s[2][r], s[3][r]));
      m = fmaxf(m, __shfl_xor(m, 1, 64));
      m = fmaxf(m, __shfl_xor(m, 2, 64));
      m = fmaxf(m, __shfl_xor(m, 4, 64));
      m = fmaxf(m, __shfl_xor(m, 8, 64));
      mx[r] = m;
    }
    #pragma unroll
    for (int ct = 0; ct < 4; ++ct)
      #pragma unroll
      for (int r = 0; r < 4; ++r)
        s[ct][r] = __expf(s[ct][r] - mx[r]);
    #pragma unroll
    for (int r = 0; r < 4; ++r) {
      float t = s[0][r] + s[1][r] + s[2][r] + s[3][r];
      t += __shfl_xor(t, 1, 64);
      t += __shfl_xor(t, 2, 64);
      t += __shfl_xor(t, 4, 64);
      t += __shfl_xor(t, 8, 64);
      si[r] = __builtin_amdgcn_rcpf(t);
    }
    #pragma unroll
    for (int ct = 0; ct < 4; ++ct)
      #pragma unroll
      for (int r = 0; r < 4; ++r)
        *(short*)(spc + sp_b(w, lg * 4 + r, ct * 16 + lr)) =
            (short)f2bf_u(s[ct][r] * si[r]);
    #pragma unroll
    for (int kk = 0; kk < 2; ++kk) {
      const bf16x8 pa = *(const bf16x8*)(spc + sp_b(w, lr, kk * 32 + lg * 8));
      #pragma unroll
      for (int jt = 0; jt < 2; ++jt) {
        const bf16x8 vb = *(const bf16x8*)(svc + sv_b(h * 32 + jt * 16 + lr, kk * 32 + lg * 8));
        oacc[hh][jt] = __builtin_amdgcn_mfma_f32_16x16x32_bf16(pa, vb, oacc[hh][jt], 0, 0, 0);
      }
    }
  }

  __syncthreads();
  #pragma unroll
  for (int hh = 0; hh < 4; ++hh)
    #pragma unroll
    for (int jt = 0; jt < 2; ++jt)
      #pragma unroll
      for (int r = 0; r < 4; ++r)
        *(short*)(sxc + sx_b(r0 + lg * 4 + r, (hb + hh) * 32 + jt * 16 + lr)) =
            (short)f2bf_u(oacc[hh][jt][r]);
  __syncthreads();

  gemm32(sxc, wp, proj_b, acc, w, lr, lg);

  float* og = out + (size_t)b * NTOK * CDIM;
  #pragma unroll
  for (int half = 0; half < 2; ++half) {
    if ((w >> 2) == half) {
      const int wc = (w & 3) * 32;
      #pragma unroll
      for (int rt = 0; rt < 4; ++rt)
        #pragma unroll
        for (int ct = 0; ct < 2; ++ct)
          #pragma unroll
          for (int r = 0; r < 4; ++r)
            *(float*)(svc + so_b(rt * 16 + lg * 4 + r, wc + ct * 16 + lr)) = acc[rt][ct][r];
    }
    __syncthreads();
    for (int i = tid; i < NTOK * 32; i += 512) {
      const int row = i >> 5, c4 = i & 31;
      const float4 v = *(const float4*)(svc + so_b(row, c4 * 4));
      *(float4*)(og + row * CDIM + half * 128 + c4 * 4) = v;
    }
    __syncthreads();
  }
}

extern "C" void kernel_launch(void* const* d_in, const int* in_sizes, int n_in,
                              void* d_out, int out_size, void* d_ws, size_t ws_size,
                              hipStream_t stream) {
  const float* x1     = (const float*)d_in[0];
  const float* x2     = (const float*)d_in[1];
  const float* qkv_w  = (const float*)d_in[2];
  const float* qkv_b  = (const float*)d_in[3];
  const float* proj_w = (const float*)d_in[4];
  const float* proj_b = (const float*)d_in[5];
  const float* rpb    = (const float*)d_in[6];
  const int*   rel    = (const int*)d_in[7];

  char* ws = (char*)d_ws;
  short* wqkv     = (short*)ws;                         // 393216 B
  short* wp       = (short*)(ws + 393216);              // 131072 B
  float* bias_s   = (float*)(ws + 524288);              // 3072 B
  float* bias_att = (float*)(ws + 527360);              // 131072 B
  char*  img      = ws + 658432;                        // Bn * 96 KB images

  const int prep_total = 768 * 256 + 256 * 256 + 768 + NH * NP * NP;
  prep_kernel<<<(prep_total + 255) / 256, 256, 0, stream>>>(
      qkv_w, qkv_b, proj_w, rpb, rel, wqkv, wp, bias_s, bias_att);

  const int Bn = in_sizes[0] / (NTOK * CDIM);
  const size_t need = 658432 + (size_t)Bn * IMG_STRIDE;

  if (ws_size >= need) {
    (void)hipFuncSetAttribute((const void*)qkv_kernel,
                              hipFuncAttributeMaxDynamicSharedMemorySize, 65536);
    (void)hipFuncSetAttribute((const void*)attnproj_kernel,
                              hipFuncAttributeMaxDynamicSharedMemorySize, 40960);
    qkv_kernel<<<Bn, 512, 65536, stream>>>(x1, x2, wqkv, bias_s, img);
    attnproj_kernel<<<Bn, 256, 40960, stream>>>(img, wp, proj_b, bias_att, (float*)d_out);
  } else {
    const size_t shmem = SX_BYTES + SV_BYTES + SP_BYTES;  // 81920
    (void)hipFuncSetAttribute((const void*)fused_attn,
                              hipFuncAttributeMaxDynamicSharedMemorySize, (int)shmem);
    fused_attn<<<Bn, 512, shmem, stream>>>(x1, x2, wqkv, bias_s, wp, proj_b, bias_att,
                                           (float*)d_out);
  }
}